// Round 2
// baseline (546.908 us; speedup 1.0000x reference)
//
#include <hip/hip_runtime.h>

// 2-layer GCN, algebraically collapsed to scalar per-node quantities.
// deg[d] = (# edges with dst==d) + 1 (self loop); dis = 1/sqrt(deg)
// s[d]   = dis[d] * ( sum_{e->d} x[src]*dis[src] + x[d]*dis[d] )
// g[d]   = sum_j relu(s[d]*W1[j] + b1[j]) * W2[j]
// out[d] = dis[d] * ( sum_{e->d} g[src]*dis[src] + g[d]*dis[d] ) + b2
//
// NOTE: edge_index arrives as int32 (harness delivers JAX default-x64-off
// integers as int32) — casting to long long caused the R1 OOB abort.

__global__ void degree_k(const int* __restrict__ dst, int E,
                         unsigned int* __restrict__ deg) {
    int i = blockIdx.x * blockDim.x + threadIdx.x;
    if (i < E) {
        atomicAdd(&deg[dst[i]], 1u);
    }
}

__global__ void prep1_k(const float* __restrict__ x,
                        const unsigned int* __restrict__ deg,
                        float* __restrict__ dis, float* __restrict__ y, int N) {
    int i = blockIdx.x * blockDim.x + threadIdx.x;
    if (i < N) {
        float d = (float)(deg[i] + 1u);   // +1 self loop
        float r = 1.0f / sqrtf(d);
        dis[i] = r;
        y[i] = x[i] * r;
    }
}

__global__ void scatter_k(const int* __restrict__ src,
                          const int* __restrict__ dst,
                          const float* __restrict__ val,
                          float* __restrict__ acc, int E) {
    int i = blockIdx.x * blockDim.x + threadIdx.x;
    if (i < E) {
        atomicAdd(&acc[dst[i]], val[src[i]]);
    }
}

__global__ void prep2_k(const float* __restrict__ dis,
                        const float* __restrict__ y,
                        const float* __restrict__ t,
                        const float* __restrict__ W1,
                        const float* __restrict__ b1,
                        const float* __restrict__ W2,
                        float* __restrict__ z, int N, int H) {
    extern __shared__ float smem[];
    float* sW1 = smem;
    float* sb1 = smem + H;
    float* sW2 = smem + 2 * H;
    for (int j = threadIdx.x; j < H; j += blockDim.x) {
        sW1[j] = W1[j];
        sb1[j] = b1[j];
        sW2[j] = W2[j];
    }
    __syncthreads();
    int i = blockIdx.x * blockDim.x + threadIdx.x;
    if (i >= N) return;
    float r = dis[i];
    float s = r * (t[i] + y[i]);   // layer-1 pre-activation scale
    float g = 0.0f;
    #pragma unroll 8
    for (int j = 0; j < H; j++) {
        float h = s * sW1[j] + sb1[j];
        h = h > 0.0f ? h : 0.0f;   // relu
        g += h * sW2[j];
    }
    z[i] = g * r;   // pre-scaled message for layer 2
}

__global__ void final_k(const float* __restrict__ dis,
                        const float* __restrict__ z,
                        const float* __restrict__ u,
                        const float* __restrict__ b2,
                        float* __restrict__ out, int N) {
    int i = blockIdx.x * blockDim.x + threadIdx.x;
    if (i < N) {
        out[i] = dis[i] * (u[i] + z[i]) + b2[0];
    }
}

extern "C" void kernel_launch(void* const* d_in, const int* in_sizes, int n_in,
                              void* d_out, int out_size, void* d_ws, size_t ws_size,
                              hipStream_t stream) {
    const float* x   = (const float*)d_in[0];
    const int*   ei  = (const int*)d_in[1];     // int32! (see note above)
    const float* W1  = (const float*)d_in[2];
    const float* b1  = (const float*)d_in[3];
    const float* W2  = (const float*)d_in[4];
    const float* b2  = (const float*)d_in[5];
    float*       out = (float*)d_out;

    const int N = in_sizes[0];        // 100000 (x is [N,1])
    const int E = in_sizes[1] / 2;    // 3200000
    const int H = in_sizes[2];        // 256

    const int* srcp = ei;             // edge_index[0]
    const int* dstp = ei + E;         // edge_index[1]

    // workspace layout (all 4-byte slots):
    // [deg u32: N][t f32: N][u f32: N][dis f32: N][y f32: N][z f32: N]
    float* ws = (float*)d_ws;
    unsigned int* deg = (unsigned int*)ws;
    float* t   = ws + (size_t)N;
    float* u   = ws + (size_t)2 * N;
    float* dis = ws + (size_t)3 * N;
    float* y   = ws + (size_t)4 * N;
    float* z   = ws + (size_t)5 * N;

    // zero the three accumulators in one memset (they are contiguous)
    hipMemsetAsync(d_ws, 0, (size_t)3 * N * sizeof(float), stream);

    const int TB = 256;
    const int gE = (E + TB - 1) / TB;
    const int gN = (N + TB - 1) / TB;

    degree_k<<<gE, TB, 0, stream>>>(dstp, E, deg);
    prep1_k<<<gN, TB, 0, stream>>>(x, deg, dis, y, N);
    scatter_k<<<gE, TB, 0, stream>>>(srcp, dstp, y, t, E);
    prep2_k<<<gN, TB, (size_t)3 * H * sizeof(float), stream>>>(dis, y, t, W1, b1, W2, z, N, H);
    scatter_k<<<gE, TB, 0, stream>>>(srcp, dstp, z, u, E);
    final_k<<<gN, TB, 0, stream>>>(dis, z, u, b2, out, N);
}